// Round 2
// baseline (1451.568 us; speedup 1.0000x reference)
//
#include <hip/hip_runtime.h>

#define NDIM 14
#define HDIM 64

static __device__ __forceinline__ float sigmoidf_(float x) { return 1.f / (1.f + expf(-x)); }

// Shared epilogue: v = AGG/(DEN+eps) + bias, ELU, LayerNorm. Wave-per-node, lane j.
static __device__ __forceinline__ float node_epilogue(
    const float* __restrict__ AGG, const float* __restrict__ DEN,
    const float* __restrict__ gb, const float* __restrict__ lng,
    const float* __restrict__ lnb, int n, int j) {
  int h = j >> 5;
  float v = AGG[n * HDIM + j] / (DEN[n * 2 + h] + 1e-16f) + gb[j];
  v = v > 0.f ? v : expf(v) - 1.f;          // ELU
  float s = v;
#pragma unroll
  for (int m = 32; m >= 1; m >>= 1) s += __shfl_xor(s, m, 64);
  float mu = s * (1.f / 64.f);
  float d = v - mu;
  float sq = d * d;
#pragma unroll
  for (int m = 32; m >= 1; m >>= 1) sq += __shfl_xor(sq, m, 64);
  float var = sq * (1.f / 64.f);
  return d * rsqrtf(var + 1e-5f) * lng[j] + lnb[j];
}

// Dual 64x64 matvec via shuffle broadcast: al_j = sum_k x_k Wl[k][j], ar likewise.
static __device__ __forceinline__ void dual_matvec(
    float xj, const float* __restrict__ Wl, const float* __restrict__ Wr,
    int j, float& al, float& ar) {
  al = 0.f; ar = 0.f;
#pragma unroll
  for (int k = 0; k < HDIM; ++k) {
    float xk = __shfl(xj, k, 64);
    al += xk * Wl[k * HDIM + j];
    ar += xk * Wr[k * HDIM + j];
  }
}

// ---------- K1: proj + GAT1 Wl/Wr + zero AGG/DEN ----------
__global__ void k1_proj_lr(const float* __restrict__ nf, const float* __restrict__ W,
                           const float* __restrict__ b, const float* __restrict__ Wl,
                           const float* __restrict__ Wr, float* __restrict__ XL,
                           float* __restrict__ XR, float* __restrict__ AGG,
                           float* __restrict__ DEN, int N) {
  int n = blockIdx.x * (blockDim.x >> 6) + (threadIdx.x >> 6);
  int j = threadIdx.x & 63;
  if (n >= N) return;
  float nfv = (j < NDIM) ? nf[n * NDIM + j] : 0.f;
  float xj = b[j];
#pragma unroll
  for (int k = 0; k < NDIM; ++k) xj += __shfl(nfv, k, 64) * W[k * HDIM + j];
  float al, ar;
  dual_matvec(xj, Wl, Wr, j, al, ar);
  XL[n * HDIM + j] = al;
  XR[n * HDIM + j] = ar;
  AGG[n * HDIM + j] = 0.f;
  if (j < 2) DEN[n * 2 + j] = 0.f;
}

// ---------- K2/K4: fused edge pass: score + exp + scatter-accumulate ----------
// wave per edge; lane = h*32 + c
__global__ void k_edge(const int* __restrict__ ei, const float* __restrict__ XL,
                       const float* __restrict__ XR, const float* __restrict__ att,
                       float* __restrict__ DEN, float* __restrict__ AGG, int E, int N) {
  int e = blockIdx.x * (blockDim.x >> 6) + (threadIdx.x >> 6);
  int lane = threadIdx.x & 63;
  int EP = E + N;
  if (e >= EP) return;
  int s_, d_;
  if (e < E) { s_ = ei[e]; d_ = ei[E + e]; } else { s_ = d_ = e - E; }
  float xlv = XL[s_ * HDIM + lane];
  float v = xlv + XR[d_ * HDIM + lane];
  v = v > 0.f ? v : 0.2f * v;               // leaky_relu
  float p = v * att[lane];                  // att[h*32+c] == att[lane]
#pragma unroll
  for (int m = 16; m >= 1; m >>= 1) p += __shfl_xor(p, m, 64);
  // after butterfly, every lane in each 32-half holds its head's score
  float ex = expf(p);
  if ((lane & 31) == 0) atomicAdd(&DEN[d_ * 2 + (lane >> 5)], ex);
  atomicAdd(&AGG[d_ * HDIM + lane], ex * xlv);
}

// ---------- K3: GAT1 epilogue + GAT2 Wl/Wr + zero AGG2/DEN2 ----------
__global__ void k3_node_lr(const float* __restrict__ AGG, const float* __restrict__ DEN,
                           const float* __restrict__ gb, const float* __restrict__ lng,
                           const float* __restrict__ lnb, const float* __restrict__ Wl,
                           const float* __restrict__ Wr, float* __restrict__ XL,
                           float* __restrict__ XR, float* __restrict__ AGG2,
                           float* __restrict__ DEN2, int N) {
  int n = blockIdx.x * (blockDim.x >> 6) + (threadIdx.x >> 6);
  int j = threadIdx.x & 63;
  if (n >= N) return;
  float y = node_epilogue(AGG, DEN, gb, lng, lnb, n, j);
  float al, ar;
  dual_matvec(y, Wl, Wr, j, al, ar);
  XL[n * HDIM + j] = al;
  XR[n * HDIM + j] = ar;
  AGG2[n * HDIM + j] = 0.f;
  if (j < 2) DEN2[n * 2 + j] = 0.f;
}

// ---------- K5: GAT2 epilogue + GRU (h0=0) + 4 heads ----------
__global__ void k5_node_gru(const float* __restrict__ AGG, const float* __restrict__ DEN,
                            const float* __restrict__ gb, const float* __restrict__ lng,
                            const float* __restrict__ lnb, const float* __restrict__ Wi,
                            const float* __restrict__ bi, const float* __restrict__ bh,
                            const float* __restrict__ huW, const float* __restrict__ hub,
                            const float* __restrict__ hfW, const float* __restrict__ hfb,
                            const float* __restrict__ hoW, const float* __restrict__ hob,
                            const float* __restrict__ hcW, const float* __restrict__ hcb,
                            float* __restrict__ out, int N) {
  int n = blockIdx.x * (blockDim.x >> 6) + (threadIdx.x >> 6);
  int j = threadIdx.x & 63;
  if (n >= N) return;
  float y = node_epilogue(AGG, DEN, gb, lng, lnb, n, j);
  float ar = 0.f, az = 0.f, an = 0.f;
#pragma unroll
  for (int k = 0; k < HDIM; ++k) {
    float xk = __shfl(y, k, 64);
    ar += xk * Wi[k * 192 + j];
    az += xk * Wi[k * 192 + 64 + j];
    an += xk * Wi[k * 192 + 128 + j];
  }
  float r = sigmoidf_(ar + bi[j] + bh[j]);
  float z = sigmoidf_(az + bi[64 + j] + bh[64 + j]);
  float nn = tanhf(an + bi[128 + j] + r * bh[128 + j]);
  float hv = (1.f - z) * nn;
  float pu = hv * huW[j], pf = hv * hfW[j], po = hv * hoW[j], pc = hv * hcW[j];
#pragma unroll
  for (int m = 32; m >= 1; m >>= 1) {
    pu += __shfl_xor(pu, m, 64);
    pf += __shfl_xor(pf, m, 64);
    po += __shfl_xor(po, m, 64);
    pc += __shfl_xor(pc, m, 64);
  }
  if (j == 0) {
    out[n]         = sigmoidf_(pu + hub[0]);
    out[N + n]     = sigmoidf_(pf + hfb[0]);
    out[2 * N + n] = fmaxf(po + hob[0], 0.f);
    out[3 * N + n] = sigmoidf_(pc + hcb[0]);
  }
}

// ---------- launch ----------
extern "C" void kernel_launch(void* const* d_in, const int* in_sizes, int n_in,
                              void* d_out, int out_size, void* d_ws, size_t ws_size,
                              hipStream_t stream) {
  const float* nf    = (const float*)d_in[0];
  const int*   ei    = (const int*)d_in[1];
  const float* projW = (const float*)d_in[2];
  const float* projB = (const float*)d_in[3];
  const float* g1Wl  = (const float*)d_in[4];
  const float* g1Wr  = (const float*)d_in[5];
  const float* g1att = (const float*)d_in[6];
  const float* g1b   = (const float*)d_in[7];
  const float* g2Wl  = (const float*)d_in[8];
  const float* g2Wr  = (const float*)d_in[9];
  const float* g2att = (const float*)d_in[10];
  const float* g2b   = (const float*)d_in[11];
  const float* ln1g  = (const float*)d_in[12];
  const float* ln1b  = (const float*)d_in[13];
  const float* ln2g  = (const float*)d_in[14];
  const float* ln2b  = (const float*)d_in[15];
  const float* gruWi = (const float*)d_in[16];
  // d_in[17] = gru_Wh, unused (h0 = 0)
  const float* gruBi = (const float*)d_in[18];
  const float* gruBh = (const float*)d_in[19];
  const float* huW = (const float*)d_in[20];
  const float* hub = (const float*)d_in[21];
  const float* hfW = (const float*)d_in[22];
  const float* hfb = (const float*)d_in[23];
  const float* hoW = (const float*)d_in[24];
  const float* hob = (const float*)d_in[25];
  const float* hcW = (const float*)d_in[26];
  const float* hcb = (const float*)d_in[27];
  float* out = (float*)d_out;

  const int N = in_sizes[0] / NDIM;
  const int E = in_sizes[1] / 2;
  const int EP = E + N;

  // workspace carve-up
  char* ws = (char*)d_ws;
  size_t off = 0;
  auto carve = [&](size_t bytes) { void* p = ws + off; off += (bytes + 255) & ~size_t(255); return p; };
  float* XL  = (float*)carve(sizeof(float) * N * HDIM);
  float* XR  = (float*)carve(sizeof(float) * N * HDIM);
  float* AGG = (float*)carve(sizeof(float) * N * HDIM);
  float* DEN = (float*)carve(sizeof(float) * N * 2);

  const int BLK = 256;
  dim3 b(BLK);
  dim3 gridWaveN((N + 3) / 4);                     // wave per node
  dim3 gridWaveE((EP + 3) / 4);                    // wave per edge

  // ---- proj + GAT layer 1 lin ----
  k1_proj_lr<<<gridWaveN, b, 0, stream>>>(nf, projW, projB, g1Wl, g1Wr, XL, XR, AGG, DEN, N);
  // ---- GAT layer 1 edge ----
  k_edge<<<gridWaveE, b, 0, stream>>>(ei, XL, XR, g1att, DEN, AGG, E, N);
  // ---- GAT1 epilogue + GAT layer 2 lin (reuses XL/XR; re-zeros AGG/DEN after reading) ----
  // NOTE: k3 reads AGG/DEN for node n then overwrites its own slots only -> safe.
  k3_node_lr<<<gridWaveN, b, 0, stream>>>(AGG, DEN, g1b, ln1g, ln1b, g2Wl, g2Wr, XL, XR, AGG, DEN, N);
  // ---- GAT layer 2 edge ----
  k_edge<<<gridWaveE, b, 0, stream>>>(ei, XL, XR, g2att, DEN, AGG, E, N);
  // ---- GAT2 epilogue + GRU + heads ----
  k5_node_gru<<<gridWaveN, b, 0, stream>>>(AGG, DEN, g2b, ln2g, ln2b,
                                           gruWi, gruBi, gruBh,
                                           huW, hub, hfW, hfb, hoW, hob, hcW, hcb,
                                           out, N);
}